// Round 6
// baseline (336.908 us; speedup 1.0000x reference)
//
#include <hip/hip_runtime.h>
#include <math.h>

typedef __attribute__((ext_vector_type(8))) short short8;      // 8 bf16 (4 VGPRs) MFMA operand
typedef __attribute__((ext_vector_type(4))) float floatx4;     // 16x16 MFMA accumulator
typedef __attribute__((ext_vector_type(16))) float floatx16;   // 32x32 MFMA accumulator
typedef __attribute__((ext_vector_type(8))) unsigned short ushort8v;
typedef __attribute__((ext_vector_type(4))) unsigned short ushort4v;

#define HW 4096
#define CCH 512
#define NB 4
#define NH 4
#define HD 128

__device__ __forceinline__ unsigned short f2bf(float f) {
    union { float f; unsigned int u; } c; c.f = f;
    unsigned int u = c.u;
    u += 0x7FFFu + ((u >> 16) & 1u);   // round-to-nearest-even
    return (unsigned short)(u >> 16);
}

// async global->LDS DMA, 16B per lane. LDS dest = wave-uniform base + lane*16 (linear);
// swizzled layouts are achieved by permuting the per-lane GLOBAL source address.
__device__ __forceinline__ void gload_lds16(const unsigned short* g, unsigned short* l) {
    __builtin_amdgcn_global_load_lds(
        (const __attribute__((address_space(1))) unsigned int*)g,
        (__attribute__((address_space(3))) unsigned int*)l, 16, 0, 0);
}

__device__ __forceinline__ float sum16(const floatx16& s) {
    return ((((s[0] + s[1]) + (s[2] + s[3])) + ((s[4] + s[5]) + (s[6] + s[7])))
          + (((s[8] + s[9]) + (s[10] + s[11])) + ((s[12] + s[13]) + (s[14] + s[15]))));
}

// ---------------- weights fp32 -> bf16 ----------------
__global__ void conv_w(const float* __restrict__ w0, const float* __restrict__ w1,
                       const float* __restrict__ w2, const float* __restrict__ w3,
                       unsigned short* __restrict__ dst) {
    const float* src = blockIdx.y == 0 ? w0 : blockIdx.y == 1 ? w1 : blockIdx.y == 2 ? w2 : w3;
    unsigned short* d = dst + (size_t)blockIdx.y * 262144;
    int i = blockIdx.x * 256 + threadIdx.x;          // float4 index, 65536 total
    float4 v = ((const float4*)src)[i];
    ushort4v o;
    o[0] = f2bf(v.x); o[1] = f2bf(v.y); o[2] = f2bf(v.z); o[3] = f2bf(v.w);
    ((ushort4v*)d)[i] = o;
}

// ---------------- GroupNorm stats: one block per (b, group) ----------------
__global__ void gn_stats(const float* __restrict__ x, float* __restrict__ stats) {
    int bg = blockIdx.x;                 // 0..127
    int b = bg >> 5, g = bg & 31;
    const float4* p = (const float4*)(x + ((size_t)b * CCH + g * 16) * HW);  // 16 ch * 4096 contiguous
    float s = 0.f, ss = 0.f;
    for (int i = threadIdx.x; i < 16384; i += 256) {
        float4 v = p[i];
        s  += v.x + v.y + v.z + v.w;
        ss += v.x * v.x + v.y * v.y + v.z * v.z + v.w * v.w;
    }
    #pragma unroll
    for (int off = 32; off > 0; off >>= 1) {
        s  += __shfl_down(s, off, 64);
        ss += __shfl_down(ss, off, 64);
    }
    __shared__ float sm[4], sm2[4];
    int wid = threadIdx.x >> 6;
    if ((threadIdx.x & 63) == 0) { sm[wid] = s; sm2[wid] = ss; }
    __syncthreads();
    if (threadIdx.x == 0) {
        float ts = sm[0] + sm[1] + sm[2] + sm[3];
        float tss = sm2[0] + sm2[1] + sm2[2] + sm2[3];
        float mean = ts * (1.f / 65536.f);
        float var = tss * (1.f / 65536.f) - mean * mean;
        stats[bg * 2] = mean;
        stats[bg * 2 + 1] = rsqrtf(var + 1e-5f);
    }
}

// ---------------- normalize + transpose -> XT[b, s, c] bf16 ----------------
__global__ void gn_apply(const float* __restrict__ x, const float* __restrict__ gnw,
                         const float* __restrict__ gnb, const float* __restrict__ stats,
                         unsigned short* __restrict__ xt) {
    int s = blockIdx.x * 256 + threadIdx.x;   // 0..4095
    int g = blockIdx.y, b = blockIdx.z;
    float mean = stats[(b * 32 + g) * 2];
    float rstd = stats[(b * 32 + g) * 2 + 1];
    const float* xb = x + ((size_t)b * CCH + g * 16) * HW + s;
    unsigned short outv[16];
    #pragma unroll
    for (int cl = 0; cl < 16; cl++) {
        int c = g * 16 + cl;
        float v = xb[(size_t)cl * HW];                       // lanes->consecutive s: coalesced
        v = (v - mean) * rstd * gnw[c] + gnb[c];
        outv[cl] = f2bf(v);
    }
    unsigned short* dst = xt + ((size_t)b * HW + s) * CCH + g * 16;   // 32B contiguous per thread
    *(ushort8v*)dst       = *(ushort8v*)&outv[0];
    *(ushort8v*)(dst + 8) = *(ushort8v*)&outv[8];
}

// ---------------- NT GEMM: C[m,n] = sum_k A[m,k] B[n,k], K=512 ----------------
// MODE 0: C bf16 [m,n], bias per-col n, *scale      (single projection)
// MODE 1: C fp32 [m,n], bias per-row m, + residual  (output projection + residual)
// MODE 2: C bf16 [m,n], bias per-row m              (V projection, stored transposed)
// MODE 3: like MODE 0 but dual-launch over z: z=0 -> (bias, scale); z=1 -> (resid-as-bias, 1.0)
//         with B and C strided by z (Q and K projections fused into one dispatch).
// Reg-prefetch + LDS double-buffer: ONE barrier per K-step, global latency hidden under MFMA.
#define LDP 72   // padded leading dim (ushorts): 72*2=144B, 16B-aligned, 36 dwords == 4 mod 32 banks
template <int MODE>
__global__ __launch_bounds__(256, 2) void gemm_nt(
    const unsigned short* __restrict__ A, long long aStride,
    const unsigned short* __restrict__ Bm, long long bStride,
    const float* __restrict__ bias, float scale,
    const float* __restrict__ resid, long long rStride,
    void* __restrict__ Cp, long long cStride, int ldc) {
    __shared__ unsigned short lA[2][128 * LDP];
    __shared__ unsigned short lB[2][128 * LDP];
    const int tid = threadIdx.x;
    const int lane = tid & 63;
    const int wid = tid >> 6;
    const int z = blockIdx.z;
    const unsigned short* Ab = A + (size_t)z * aStride + (size_t)blockIdx.x * 128 * 512;
    const unsigned short* Bb = Bm + (size_t)z * bStride + (size_t)blockIdx.y * 128 * 512;

    floatx4 acc[4][4];
    #pragma unroll
    for (int i = 0; i < 4; i++)
        #pragma unroll
        for (int j = 0; j < 4; j++) acc[i][j] = (floatx4)0.f;

    const int wm = (wid >> 1) * 64;
    const int wn = (wid & 1) * 64;
    const int l15 = lane & 15;
    const int l4 = lane >> 4;
    const int srow = tid >> 3;            // 0..31 base row block (idx>>3 for i=0)
    const int skc  = (tid & 7) * 8;       // k-chunk within 64

    ushort8v ar[4], br[4];
    // prologue: tile 0 -> regs -> LDS buf 0
    #pragma unroll
    for (int i = 0; i < 4; i++) {
        int row = srow + i * 32;
        ar[i] = *(const ushort8v*)&Ab[(size_t)row * 512 + skc];
        br[i] = *(const ushort8v*)&Bb[(size_t)row * 512 + skc];
    }
    #pragma unroll
    for (int i = 0; i < 4; i++) {
        int row = srow + i * 32;
        *(ushort8v*)&lA[0][row * LDP + skc] = ar[i];
        *(ushort8v*)&lB[0][row * LDP + skc] = br[i];
    }
    __syncthreads();

    int cur = 0;
    #pragma unroll 1
    for (int t = 0; t < 8; t++) {
        // prefetch next K-tile into regs (latency hides under the MFMAs below)
        if (t < 7) {
            int k0 = (t + 1) * 64;
            #pragma unroll
            for (int i = 0; i < 4; i++) {
                int row = srow + i * 32;
                ar[i] = *(const ushort8v*)&Ab[(size_t)row * 512 + k0 + skc];
                br[i] = *(const ushort8v*)&Bb[(size_t)row * 512 + k0 + skc];
            }
        }
        #pragma unroll
        for (int kk = 0; kk < 2; kk++) {
            short8 af[4], bf[4];
            #pragma unroll
            for (int i = 0; i < 4; i++)
                af[i] = *(const short8*)&lA[cur][(wm + i * 16 + l15) * LDP + kk * 32 + l4 * 8];
            #pragma unroll
            for (int j = 0; j < 4; j++)
                bf[j] = *(const short8*)&lB[cur][(wn + j * 16 + l15) * LDP + kk * 32 + l4 * 8];
            #pragma unroll
            for (int i = 0; i < 4; i++)
                #pragma unroll
                for (int j = 0; j < 4; j++)
                    acc[i][j] = __builtin_amdgcn_mfma_f32_16x16x32_bf16(af[i], bf[j], acc[i][j], 0, 0, 0);
        }
        if (t < 7) {
            int nxt = cur ^ 1;
            #pragma unroll
            for (int i = 0; i < 4; i++) {
                int row = srow + i * 32;
                *(ushort8v*)&lA[nxt][row * LDP + skc] = ar[i];
                *(ushort8v*)&lB[nxt][row * LDP + skc] = br[i];
            }
            __syncthreads();
            cur = nxt;
        }
    }

    long long m0 = (long long)blockIdx.x * 128 + wm;
    long long n0 = (long long)blockIdx.y * 128 + wn;
    if (MODE == 0 || MODE == 3) {
        unsigned short* C = (unsigned short*)Cp + (size_t)z * cStride;
        const float* bptr = (MODE == 3 && z == 1) ? resid : bias;
        float sc = (MODE == 3 && z == 1) ? 1.f : scale;
        #pragma unroll
        for (int i = 0; i < 4; i++)
            #pragma unroll
            for (int j = 0; j < 4; j++) {
                long long col = n0 + j * 16 + l15;
                float bv = bptr[col];
                #pragma unroll
                for (int r = 0; r < 4; r++) {
                    long long row = m0 + i * 16 + l4 * 4 + r;    // D: row=(lane>>4)*4+reg, col=lane&15
                    C[row * ldc + col] = f2bf((acc[i][j][r] + bv) * sc);
                }
            }
    } else if (MODE == 1) {
        float* C = (float*)Cp + (size_t)z * cStride;
        const float* R = resid + (size_t)z * rStride;
        #pragma unroll
        for (int i = 0; i < 4; i++)
            #pragma unroll
            for (int j = 0; j < 4; j++)
                #pragma unroll
                for (int r = 0; r < 4; r++) {
                    long long row = m0 + i * 16 + l4 * 4 + r;    // row = output channel o
                    long long col = n0 + j * 16 + l15;           // col = spatial s (coalesced)
                    C[row * ldc + col] = acc[i][j][r] + bias[row] + R[row * ldc + col];
                }
    } else {
        unsigned short* C = (unsigned short*)Cp + (size_t)z * cStride;
        #pragma unroll
        for (int i = 0; i < 4; i++)
            #pragma unroll
            for (int j = 0; j < 4; j++)
                #pragma unroll
                for (int r = 0; r < 4; r++) {
                    long long row = m0 + i * 16 + l4 * 4 + r;    // row = channel c (V^T layout)
                    long long col = n0 + j * 16 + l15;           // col = spatial s
                    C[row * ldc + col] = f2bf(acc[i][j][r] + bias[row]);
                }
    }
}

// ---------------- flash attention (no-max, 32x32 MFMA, DMA-staged, parity-pipelined) ----------------
// One block per (q-tile 128, head, batch). Q pre-scaled by log2(e)/sqrt(hd) -> p = exp2(S).
//
// Staging via global_load_lds (async DMA): linear LDS dest, XOR-swizzled per-lane GLOBAL source
// (same maps as R5; read-side banks spread 8 groups x 2 lanes per 16-lane phase).
//
// PARITY PIPELINE (this round): S double-buffered (saA/saB by kt parity, 2x-unrolled loop) so
// the per-step order is:  DMA issue -> QK(kt+1) writes saNEW -> pack(kt) reads saOLD -> PV(kt)
// -> barrier.  pack has NO WAR hazard against QK anymore, so its ~100 VALU ops issue in the
// shadow of the 16 QK MFMAs (separate pipes) instead of draining the matrix pipe every kt.
//
// lsum OFF the MFMA pipe: f32 add-tree over the exp2 outputs (per-lane partial over its 32
// t-slots, accumulated across kt; S^T layout -> lane l31 owns col q=l31). Final: one
// permlane32_swap + add -> lsum[q=l31] in every lane; epilogue redistributes to D-row layout
// with 16 __shfl. Saves 4 MFMA/wave/kt (11% of matrix-pipe work) + 16 VGPR (acc_l).
//
// __launch_bounds__(256,2): peak VGPR ~190 (acc_o 64 + saA/saB 64 + qf 32 + paf 16 + addr).
// (256,3) previously forced a spill (WRITE_SIZE 16K->37K) -- do NOT tighten.
__global__ __launch_bounds__(256, 2) void attn_kern(
    const unsigned short* __restrict__ Qb, const unsigned short* __restrict__ Kb,
    const unsigned short* __restrict__ Vt, unsigned short* __restrict__ Ob) {
    __shared__ __align__(16) unsigned short lk0[8192], lk1[8192];   // K tiles [64 rows][128 d] (swizzled slots)
    __shared__ __align__(16) unsigned short lv0[8192], lv1[8192];   // V tiles [128 d][64 t]   (swizzled slots)
    const int tid = threadIdx.x;
    const int lane = tid & 63;
    const int w = tid >> 6;
    const int l31 = lane & 31;
    const int l1 = lane >> 5;
    const int q0 = blockIdx.x * 128;
    const int h = blockIdx.y, b = blockIdx.z;
    const size_t headOff = (size_t)h * HD;
    const size_t batchRow = (size_t)b * HW;
    const unsigned short* VtB = Vt + ((size_t)b * CCH + headOff) * HW;  // [d][s]

    // per-thread DMA source indices (ushort units); advance by tile offset each iter
    size_t kSrc[4], vSrc[4];
    #pragma unroll
    for (int n = 0; n < 4; n++) {
        int row = w * 16 + n * 4 + (lane >> 4);
        int sk = ((row & 7) << 1) | ((row >> 3) & 1);
        int jk = (lane & 15) ^ sk;
        kSrc[n] = (batchRow + row) * 512 + headOff + jk * 8;
        int d = w * 32 + n * 8 + (lane >> 3);
        int jv = (lane & 7) ^ (d & 7);
        vSrc[n] = (size_t)d * HW + jv * 8;
    }
    const int ldsOff = w * 4 * 512;   // wave-uniform LDS chunk base (ushorts); +n*512 per load

    // read-side swizzle constants
    const int sk0 = ((l31 & 7) << 1) | ((l31 >> 3) & 1);
    const int sv0 = l31 & 7;

    // Q fragments in registers: wave w owns q-rows [w*32, w*32+32); B[n=q=l31][k=d=kd*16+l1*8+e]
    short8 qf[8];
    #pragma unroll
    for (int kd = 0; kd < 8; kd++)
        qf[kd] = *(const short8*)&Qb[(batchRow + q0 + w * 32 + l31) * 512
                                     + headOff + kd * 16 + l1 * 8];

    floatx16 acc_o[4];   // O[q][d]: col d = dj*32+l31, row q = (reg&3)+8*(reg>>2)+4*l1
    #pragma unroll
    for (int dj = 0; dj < 4; dj++) acc_o[dj] = (floatx16)0.f;
    float lsum_part = 0.f;   // per-lane partial rowsum over this lane's 32 t-slots per kt

    // prologue: DMA K(0)->lk0, K(1)->lk1, V(0)->lv0; publish; QK(0)->saA; consumption barrier
    #pragma unroll
    for (int n = 0; n < 4; n++) gload_lds16(&Kb[kSrc[n]], lk0 + ldsOff + n * 512);
    #pragma unroll
    for (int n = 0; n < 4; n++) gload_lds16(&Kb[kSrc[n] + (size_t)64 * 512], lk1 + ldsOff + n * 512);
    #pragma unroll
    for (int n = 0; n < 4; n++) gload_lds16(&VtB[vSrc[n]], lv0 + ldsOff + n * 512);
    __syncthreads();

    floatx16 saA0 = (floatx16)0.f, saA1 = (floatx16)0.f;
    floatx16 saB0, saB1;
    #pragma unroll
    for (int kd = 0; kd < 8; kd++) {
        int xk = ((kd * 2 + l1) ^ sk0) * 8;
        short8 kf0 = *(const short8*)&lk0[l31 * 128 + xk];
        short8 kf1 = *(const short8*)&lk0[l31 * 128 + xk + 4096];
        saA0 = __builtin_amdgcn_mfma_f32_32x32x16_bf16(kf0, qf[kd], saA0, 0, 0, 0);
        saA1 = __builtin_amdgcn_mfma_f32_32x32x16_bf16(kf1, qf[kd], saA1, 0, 0, 0);
    }
    __syncthreads();   // all waves done reading lk0 before step(0)'s DMA K(2)->lk0

    unsigned short* lvCur = lv0;  unsigned short* lvNxt = lv1;
    unsigned short* kRead = lk1;  unsigned short* kWrite = lk0;

    // pack(saOld) + PV from lvCur (shared by steps and tail)
    auto pack_pv = [&](floatx16& s0, floatx16& s1) {
        #pragma unroll
        for (int r = 0; r < 16; r++) s0[r] = __builtin_amdgcn_exp2f(s0[r]);
        #pragma unroll
        for (int r = 0; r < 16; r++) s1[r] = __builtin_amdgcn_exp2f(s1[r]);
        lsum_part += sum16(s0) + sum16(s1);
        short8 paf[4];
        #pragma unroll
        for (int tb = 0; tb < 2; tb++) {
            const floatx16& sa = tb ? s1 : s0;
            unsigned int wv[4][2];
            #pragma unroll
            for (int g = 0; g < 4; g++) {
                asm("v_cvt_pk_bf16_f32 %0, %1, %2" : "=v"(wv[g][0])
                    : "v"(sa[4 * g + 0]), "v"(sa[4 * g + 1]));
                asm("v_cvt_pk_bf16_f32 %0, %1, %2" : "=v"(wv[g][1])
                    : "v"(sa[4 * g + 2]), "v"(sa[4 * g + 3]));
            }
            #pragma unroll
            for (int hh = 0; hh < 2; hh++) {
                unsigned int a0 = wv[2 * hh][0], b0 = wv[2 * hh + 1][0];
                unsigned int a1 = wv[2 * hh][1], b1 = wv[2 * hh + 1][1];
                asm("v_permlane32_swap_b32 %0, %1" : "+v"(a0), "+v"(b0));
                asm("v_permlane32_swap_b32 %0, %1" : "+v"(a1), "+v"(b1));
                union { unsigned int u[4]; short8 s8; } f;
                f.u[0] = a0; f.u[1] = a1; f.u[2] = b0; f.u[3] = b1;
                paf[2 * tb + hh] = f.s8;
            }
        }
        #pragma unroll
        for (int u = 0; u < 4; u++) {
            int xv = ((u * 2 + l1) ^ sv0) * 8;
            #pragma unroll
            for (int dj = 0; dj < 4; dj++) {
                short8 vv = *(const short8*)&lvCur[dj * 2048 + l31 * 64 + xv];
                acc_o[dj] = __builtin_amdgcn_mfma_f32_32x32x16_bf16(paf[u], vv, acc_o[dj], 0, 0, 0);
            }
        }
    };

    // one pipeline step: DMA(kt+1 V, kt+2 K) -> QK(kt+1)->saNEW -> pack(kt) from saOLD -> PV(kt)
    auto step = [&](int kt, floatx16& sO0, floatx16& sO1, floatx16& sN0, floatx16& sN1) {
        size_t tv = (size_t)(kt + 1) * 64;
        size_t tk = (size_t)(kt + 2) * 64 * 512;
        #pragma unroll
        for (int n = 0; n < 4; n++) gload_lds16(&VtB[vSrc[n] + tv], lvNxt + ldsOff + n * 512);
        #pragma unroll
        for (int n = 0; n < 4; n++) gload_lds16(&Kb[kSrc[n] + tk], kWrite + ldsOff + n * 512);

        sN0 = (floatx16)0.f; sN1 = (floatx16)0.f;
        __builtin_amdgcn_s_setprio(1);
        #pragma unroll
        for (int kd = 0; kd < 8; kd++) {
            int xk = ((kd * 2 + l1) ^ sk0) * 8;
            short8 kf0 = *(const short8*)&kRead[l31 * 128 + xk];
            short8 kf1 = *(const short8*)&kRead[l31 * 128 + xk + 4096];
            sN0 = __builtin_amdgcn_mfma_f32_32x32x16_bf16(kf0, qf[kd], sN0, 0, 0, 0);
            sN1 = __builtin_amdgcn_mfma_f32_32x32x16_bf16(kf1, qf[kd], sN1, 0, 0, 0);
        }
        pack_pv(sO0, sO1);   // independent of QK above -> VALU issues in the MFMA shadow
        __builtin_amdgcn_s_setprio(0);

        __syncthreads();     // drains DMA (vmcnt) + publishes V(kt+1), K(kt+2)
        unsigned short* t_;
        t_ = lvCur; lvCur = lvNxt; lvNxt = t_;
        t_ = kRead; kRead = kWrite; kWrite = t_;
    };

    #pragma unroll 1
    for (int it = 0; it < 31; it++) {
        step(2 * it,     saA0, saA1, saB0, saB1);
        step(2 * it + 1, saB0, saB1, saA0, saA1);
    }
    step(62, saA0, saA1, saB0, saB1);   // kt=62 even: reads saA, QK(63)->saB
    // tail kt=63: pack + PV only (lvCur holds V(63), published by step(62)'s barrier)
    pack_pv(saB0, saB1);

    // lsum finalize: own-half + partner-half -> lsum[q=l31] in every lane
    float tot;
    {
        union { float f; unsigned int u; } ua, ub;
        ua.f = lsum_part; ub.f = lsum_part;
        asm("v_permlane32_swap_b32 %0, %1" : "+v"(ua.u), "+v"(ub.u));
        tot = ua.f + ub.f;   // lanes<32: own_lo+partner_hi; lanes>=32: partner_lo+own_hi
    }

    // epilogue: acc_o[dj][reg] is q-row qr = (reg&3)+8*(reg>>2)+4*l1; lsum[qr] lives in lane qr
    #pragma unroll
    for (int g = 0; g < 4; g++)
        #pragma unroll
        for (int p = 0; p < 4; p++) {
            int reg = 4 * g + p;
            int qr = p + 8 * g + 4 * l1;
            float rl = 1.f / __shfl(tot, qr, 64);
            size_t row = batchRow + q0 + w * 32 + qr;
            #pragma unroll
            for (int dj = 0; dj < 4; dj++)
                Ob[row * 512 + headOff + dj * 32 + l31] = f2bf(acc_o[dj][reg] * rl);
        }
}

extern "C" void kernel_launch(void* const* d_in, const int* in_sizes, int n_in,
                              void* d_out, int out_size, void* d_ws, size_t ws_size,
                              hipStream_t stream) {
    const float* x   = (const float*)d_in[0];
    const float* gnw = (const float*)d_in[1];
    const float* gnb = (const float*)d_in[2];
    const float* wq  = (const float*)d_in[3];
    const float* bq  = (const float*)d_in[4];
    const float* wk  = (const float*)d_in[5];
    const float* bk  = (const float*)d_in[6];
    const float* wv  = (const float*)d_in[7];
    const float* bv  = (const float*)d_in[8];
    const float* wp  = (const float*)d_in[9];
    const float* bp  = (const float*)d_in[10];
    float* out = (float*)d_out;

    const size_t NE = (size_t)NB * HW * CCH;          // 8388608 elements
    unsigned short* ws16 = (unsigned short*)d_ws;
    unsigned short* XT = ws16;                        // x_n transposed (b,s,c); reused as attn O
    unsigned short* Qb = ws16 + NE;
    unsigned short* Kb = ws16 + 2 * NE;
    unsigned short* Vt = ws16 + 3 * NE;               // V transposed: [b][c][s]
    unsigned short* Wb = ws16 + 4 * NE;               // 4 x 262144 bf16 weights
    float* stats = (float*)(ws16 + 4 * NE + 4 * 262144);

    // fold log2(e) into the attention scale so the kernel uses exp2 directly
    const float qscale = 0.08838834764831845f * 1.4426950408889634f;

    conv_w<<<dim3(256, 4), 256, 0, stream>>>(wq, wk, wv, wp, Wb);
    gn_stats<<<128, 256, 0, stream>>>(x, stats);
    gn_apply<<<dim3(16, 32, 4), 256, 0, stream>>>(x, gnw, gnb, stats, XT);

    // Q and K projections fused into one dispatch: z=0 -> Q (bias bq, *qscale), z=1 -> K (bias bk)
    gemm_nt<3><<<dim3(128, 4, 2), 256, 0, stream>>>(XT, 0, Wb, 262144, bq, qscale, bk, 0,
                                                    Qb, (long long)NE, 512);
    // V stored transposed: Vt[b][c][s] = Wv @ XT[b]^T
    gemm_nt<2><<<dim3(4, 32, 4), 256, 0, stream>>>(Wb + 2 * 262144, 0, XT, (long long)HW * 512, bv, 1.f,
                                                   nullptr, 0, Vt, (long long)CCH * HW, HW);

    unsigned short* Ob = XT;   // XT dead after QKV; reuse for attention output (b,s,c)
    attn_kern<<<dim3(32, NH, NB), 256, 0, stream>>>(Qb, Kb, Vt, Ob);

    // out[b,o,s] = sum_c wp[o,c] * Ob[b,s,c] + bp[o] + x[b,o,s]
    gemm_nt<1><<<dim3(4, 32, 4), 256, 0, stream>>>(Wb + 3 * 262144, 0, Ob, (long long)HW * 512, bp, 1.f,
                                                   x, (long long)CCH * HW, out, (long long)CCH * HW, HW);
}